// Round 25
// baseline (118.167 us; speedup 1.0000x reference)
//
// v20 — v19 with GEMM re-tiled 128x128 -> 64x128 (1152 blocks, 4.5/CU, 24KB LDS):
// occupancy-driven latency hiding for the serial K-chain. Write addressing maps
// 64-row blocks into the unchanged 128-row P tile layout. Rest identical to v19 (114.2).
#include <hip/hip_runtime.h>
#include <hip/hip_fp16.h>

#define NP 1500
#define DD 300
#define DP 320
#define VSZ 1536
#define NB 4
#define TILE 16384
#define TSZ (1536*1536)
#define OTB 16              // blocks per OT group
#define NCH 125             // colsum chunks (12 rows each)
#define KADD 1.8283051e-8f
#define PADVAL (-60000.0f)
#define SCALE 256.0f
#define SCALE2INV (1.0f/65536.0f)
#define FTHR 1e-8f

typedef _Float16 f16x8 __attribute__((ext_vector_type(8)));
typedef float f32x4 __attribute__((ext_vector_type(4)));

__device__ __forceinline__ unsigned fkey(float f){
    unsigned b = __float_as_uint(f);
    return (b & 0x80000000u) ? ~b : (b | 0x80000000u);
}
__device__ __forceinline__ float funkey(unsigned k){
    unsigned b = (k & 0x80000000u) ? (k & 0x7FFFFFFFu) : ~k;
    return __uint_as_float(b);
}

// zero nz floats then set nk uints to 0xFFFFFFFF (one launch)
__global__ void k_init(float* pz, int nz, unsigned* pk, int nk){
    int i = blockIdx.x*blockDim.x + threadIdx.x;
    if (i < nz) pz[i] = 0.f;
    int j = i - nz;
    if (j >= 0 && j < nk) pk[j] = 0xFFFFFFFFu;
}

// ---- deterministic column sums: 125 chunks x 12 rows ----
__global__ __launch_bounds__(256) void k_colsum_p1(const float* __restrict__ x, const float* __restrict__ y,
                                                   float* __restrict__ partial){
    int rc = blockIdx.x, b = blockIdx.y, src = blockIdx.z;
    const float* in = (src ? y : x) + ((size_t)b*NP + rc*12)*DD;
    int tid = threadIdx.x;
    float s0 = 0.f, s1 = 0.f;
    #pragma unroll
    for (int r = 0; r < 12; ++r){
        float v0 = in[r*DD + tid];
        s0 = fmaf(v0, v0, s0);
        if (tid < 44){
            float v1 = in[r*DD + 256 + tid];
            s1 = fmaf(v1, v1, s1);
        }
    }
    float* po = partial + (((size_t)rc*NB + b)*2 + src)*DD;
    po[tid] = s0;
    if (tid < 44) po[256 + tid] = s1;
}

__global__ void k_colsum_p2(const float* __restrict__ partial,
                            float* __restrict__ csx, float* __restrict__ csy){
    int idx = blockIdx.x*256 + threadIdx.x;
    if (idx >= NB*2*DD) return;
    int c = idx % DD; int t = idx / DD; int src = t & 1; int b = t >> 1;
    float s = 0.f;
    for (int rc = 0; rc < NCH; ++rc)
        s += partial[(((size_t)rc*NB + b)*2 + src)*DD + c];
    (src ? csy : csx)[b*DD + c] = s;
}

// ---- normalize + row-norm init; side1 seeds OT cmin buffer 2 with fkey(-(ynrm+KADD)) ----
__global__ __launch_bounds__(256) void k_normrow(const float* __restrict__ x, const float* __restrict__ y,
        const float* __restrict__ csx, const float* __restrict__ csy,
        __half* __restrict__ pxh, __half* __restrict__ pyh,
        float* __restrict__ xnrm, float* __restrict__ uvv, float* __restrict__ ynrm,
        unsigned* __restrict__ cmin){
    int gw = ((int)blockIdx.x*256 + threadIdx.x) >> 6;
    int lane = threadIdx.x & 63;
    int src = (gw >= NB*NP) ? 1 : 0;
    int rem = gw - src*NB*NP;
    int b = rem / NP, i = rem - b*NP;
    const float* in = (src ? y : x) + ((size_t)b*NP + i)*DD;
    const float* cs = (src ? csy : csx) + b*DD;
    __half* oph = (src ? pyh : pxh) + ((size_t)b*NP + i)*DP;
    float s = 0.f;
    #pragma unroll
    for (int it = 0; it < 5; ++it){
        int c = lane + it*64;
        float vu = 0.f, hv = 0.f;
        if (c < DD){
            float u = in[c];
            vu = u*u / cs[c];
            hv = vu * SCALE;
        }
        oph[c] = __float2half(hv);
        s = fmaf(vu, vu, s);
    }
    #pragma unroll
    for (int o2 = 1; o2 < 64; o2 <<= 1) s += __shfl_xor(s, o2, 64);
    if (lane == 0){
        float val = 0.5f * s;
        int o = b*VSZ + i;
        if (src){
            uvv[o] = val; ynrm[o] = val;
            cmin[(b*3 + 2)*1536 + i] = fkey(-(val + KADD));
        } else {
            xnrm[o] = val;
        }
    }
}

// ---- MFMA GEMM: kind0 only, 64x128 tiles (24 x 12 x NB blocks), BK=64, prefetch ----
__global__ __launch_bounds__(256) void k_gemm_mfma(const __half* __restrict__ pxh,
                                                   const __half* __restrict__ pyh,
                                                   __half* __restrict__ P){
    int b = blockIdx.z;
    int bx = blockIdx.x, by = blockIdx.y;
    const __half* A = pxh + (size_t)b*NP*DP;
    const __half* B = pyh + (size_t)b*NP*DP;

    __shared__ __align__(16) char smem[24576];   // A 8KB + B 16KB; epilogue 64x136x2=17.4KB overlaid
    char* ldsA = smem;                  // 64 rows x 64 halfs
    char* ldsB = smem + 8192;           // 128 rows x 64 halfs
    __half* ldsO = (__half*)smem;       // 64 x 136 halfs

    int tid = threadIdx.x;
    int row0 = bx*64, col0 = by*128;
    int lane = tid & 63;
    int w = tid >> 6;
    int wm = (w >> 1)*32, wn = (w & 1)*64;
    int g8 = tid & 7, rw = tid >> 3;    // 8 chunks x 32 rows
    int lr = lane & 15, cq = lane >> 4;

    f32x4 acc[2][4];
    #pragma unroll
    for (int mi = 0; mi < 2; ++mi)
        #pragma unroll
        for (int ni = 0; ni < 4; ++ni)
            acc[mi][ni] = (f32x4){0.f, 0.f, 0.f, 0.f};

    uint4 va[2], vb[4];
    #pragma unroll
    for (int is = 0; is < 2; ++is){
        int r = rw + is*32;
        int ar = row0 + r; if (ar > NP-1) ar = NP-1;
        va[is] = *(const uint4*)(A + (size_t)ar*DP + g8*8);
    }
    #pragma unroll
    for (int is = 0; is < 4; ++is){
        int r = rw + is*32;
        int br = col0 + r; if (br > NP-1) br = NP-1;
        vb[is] = *(const uint4*)(B + (size_t)br*DP + g8*8);
    }
    #pragma unroll
    for (int ks = 0; ks < 5; ++ks){
        if (ks) __syncthreads();
        #pragma unroll
        for (int is = 0; is < 2; ++is){
            int r = rw + is*32;
            int pc = g8 ^ (r & 7);
            *(uint4*)(ldsA + r*128 + pc*16) = va[is];
        }
        #pragma unroll
        for (int is = 0; is < 4; ++is){
            int r = rw + is*32;
            int pc = g8 ^ (r & 7);
            *(uint4*)(ldsB + r*128 + pc*16) = vb[is];
        }
        __syncthreads();
        if (ks < 4){
            int k0 = (ks + 1)*64;
            #pragma unroll
            for (int is = 0; is < 2; ++is){
                int r = rw + is*32;
                int ar = row0 + r; if (ar > NP-1) ar = NP-1;
                va[is] = *(const uint4*)(A + (size_t)ar*DP + k0 + g8*8);
            }
            #pragma unroll
            for (int is = 0; is < 4; ++is){
                int r = rw + is*32;
                int br = col0 + r; if (br > NP-1) br = NP-1;
                vb[is] = *(const uint4*)(B + (size_t)br*DP + k0 + g8*8);
            }
        }
        f16x8 av[2][2], bv[2][4];
        #pragma unroll
        for (int ksl = 0; ksl < 2; ++ksl){
            int lc = ksl*4 + cq;
            int pc = (lc ^ (lr & 7))*16;
            #pragma unroll
            for (int mi = 0; mi < 2; ++mi)
                av[ksl][mi] = *(const f16x8*)(ldsA + (wm + mi*16 + lr)*128 + pc);
            #pragma unroll
            for (int ni = 0; ni < 4; ++ni)
                bv[ksl][ni] = *(const f16x8*)(ldsB + (wn + ni*16 + lr)*128 + pc);
        }
        #pragma unroll
        for (int ksl = 0; ksl < 2; ++ksl)
            #pragma unroll
            for (int mi = 0; mi < 2; ++mi)
                #pragma unroll
                for (int ni = 0; ni < 4; ++ni)
                    acc[mi][ni] = __builtin_amdgcn_mfma_f32_16x16x32_f16(av[ksl][mi], bv[ksl][ni], acc[mi][ni], 0, 0, 0);
    }

    int cqe = lane >> 4;
    __syncthreads();
    #pragma unroll
    for (int mi = 0; mi < 2; ++mi)
        #pragma unroll
        for (int ni = 0; ni < 4; ++ni){
            int lcol = wn + ni*16 + lr;
            bool colok = (col0 + lcol) < NP;
            #pragma unroll
            for (int v = 0; v < 4; ++v){
                int lrow = wm + mi*16 + cqe*4 + v;
                bool rowok = (row0 + lrow) < NP;
                ldsO[lrow*136 + lcol] = __float2half((colok && rowok) ? acc[mi][ni][v]*SCALE2INV : PADVAL);
            }
        }
    __syncthreads();
    {
        // P tile layout: row i lives at ((i>>7)*12 + by)*TILE + (i&127)*128
        __half* tileD = P + (size_t)(b*4 + 0)*TSZ + ((size_t)(bx >> 1)*12 + by)*TILE
                        + (size_t)((bx & 1)*64)*128;
        #pragma unroll
        for (int it = 0; it < 4; ++it){
            int e = it*256 + tid;
            int r = e >> 4, q = e & 15;
            *(uint4*)(tileD + r*128 + q*8) = *(const uint4*)(ldsO + r*136 + q*8);
        }
    }
}

// ---- persistent Sinkhorn: 4 OT groups x 16 blocks (fused colmin) ----
__device__ __forceinline__ void groupbar(int* slot, int gsz){
    __syncthreads();
    if (threadIdx.x == 0){
        __hip_atomic_fetch_add(slot, 1, __ATOMIC_RELEASE, __HIP_MEMORY_SCOPE_AGENT);
        while (__hip_atomic_load(slot, __ATOMIC_ACQUIRE, __HIP_MEMORY_SCOPE_AGENT) < gsz)
            __builtin_amdgcn_s_sleep(1);
    }
    __syncthreads();
}

#define ROWPTR(PK, i) ((PK) + (size_t)((i) >> 7)*12*TILE + (size_t)((i) & 127)*128)

__global__ __launch_bounds__(1024, 1) void k_sink(const __half* __restrict__ P,
        float* __restrict__ fs, float* __restrict__ uvv,
        int* __restrict__ bars, int* __restrict__ flags,
        unsigned* __restrict__ cmin){
    int tid = threadIdx.x;
    int lane = tid & 63;
    int wid = tid >> 6;
    int blk = (int)blockIdx.x;
    __shared__ int s_ch;
    __shared__ unsigned lmin[1536];

    int b = blk / OTB, lb = blk - b*OTB;
    int gw = lb*16 + wid;
    const int NWV = OTB*16;     // 256 waves
    int* gbarp  = bars + b*64;
    int* gflagp = flags + b*64;
    const __half* P0 = P + (size_t)(b*4 + 0)*TSZ;
    float* fsb = fs + b*VSZ;
    float* uvb = uvv + b*VSZ;
    unsigned* cm = cmin + b*3*1536;

    int colb[3];
    #pragma unroll
    for (int it = 0; it < 3; ++it){
        int c = lane + it*64;
        colb[it] = ((c >> 4) << 7) + ((c & 15) << 3);
    }

    int lastT = 0;
    for (int t = 0; t < 30; ++t){
        unsigned* rdbuf = cm + ((t + 2) % 3)*1536;
        unsigned* wrbuf = cm + (t % 3)*1536;
        unsigned* rsbuf = cm + ((t + 1) % 3)*1536;
        if (tid == 0) s_ch = 0;
        for (int idx = tid; idx < 1536; idx += 1024) lmin[idx] = 0xFFFFFFFFu;
        float Au[3][8];
        #pragma unroll
        for (int it = 0; it < 3; ++it){
            uint4 k0 = *(const uint4*)(rdbuf + colb[it]);
            uint4 k1 = *(const uint4*)(rdbuf + colb[it] + 4);
            unsigned kk[8] = {k0.x, k0.y, k0.z, k0.w, k1.x, k1.y, k1.z, k1.w};
            #pragma unroll
            for (int e = 0; e < 8; ++e){
                int col = colb[it] + e;
                Au[it][e] = (col < NP) ? (-(funkey(kk[e]) + KADD)) : 3.0e38f;
            }
        }
        __syncthreads();
        float amin[3][8];
        #pragma unroll
        for (int it = 0; it < 3; ++it)
            #pragma unroll
            for (int e = 0; e < 8; ++e) amin[it][e] = 3.0e38f;
        int ch = 0;
        for (int i = gw; i < NP; i += NWV){
            const __half* rowb = ROWPTR(P0, i);
            uint4 pk[3];
            #pragma unroll
            for (int it = 0; it < 3; ++it){
                int c = lane + it*64, tt = c >> 4, q = c & 15;
                pk[it] = *(const uint4*)(rowb + (size_t)tt*TILE + q*8);
            }
            float cf[3][8];
            float m = 3.0e38f;
            #pragma unroll
            for (int it = 0; it < 3; ++it){
                float2 c0 = __half22float2(*(const __half2*)&pk[it].x);
                float2 c1 = __half22float2(*(const __half2*)&pk[it].y);
                float2 c2 = __half22float2(*(const __half2*)&pk[it].z);
                float2 c3 = __half22float2(*(const __half2*)&pk[it].w);
                cf[it][0] = c0.x; cf[it][1] = c0.y; cf[it][2] = c1.x; cf[it][3] = c1.y;
                cf[it][4] = c2.x; cf[it][5] = c2.y; cf[it][6] = c3.x; cf[it][7] = c3.y;
                #pragma unroll
                for (int e = 0; e < 8; ++e) m = fminf(m, Au[it][e] - cf[it][e]);
            }
            #pragma unroll
            for (int o = 1; o < 64; o <<= 1) m = fminf(m, __shfl_xor(m, o, 64));
            float nv = -(m + KADD);
            if (lane == 0){
                if (fabsf(nv - fsb[i]) > FTHR) ch = 1;
                fsb[i] = nv;
            }
            #pragma unroll
            for (int it = 0; it < 3; ++it)
                #pragma unroll
                for (int e = 0; e < 8; ++e)
                    amin[it][e] = fminf(amin[it][e], nv - cf[it][e]);
        }
        if (ch) s_ch = 1;
        #pragma unroll
        for (int it = 0; it < 3; ++it)
            #pragma unroll
            for (int e = 0; e < 8; ++e)
                atomicMin(&lmin[colb[it] + e], fkey(amin[it][e]));
        __syncthreads();
        for (int idx = tid; idx < 1536; idx += 1024)
            atomicMin(&wrbuf[idx], lmin[idx]);
        if (tid < 96) rsbuf[lb*96 + tid] = 0xFFFFFFFFu;
        if (tid == 0 && s_ch) atomicOr(&gflagp[t], 1);
        groupbar(&gbarp[t], OTB);
        lastT = t;
        int fA = __hip_atomic_load(&gflagp[t], __ATOMIC_RELAXED, __HIP_MEMORY_SCOPE_AGENT);
        if (fA == 0) break;
    }
    unsigned* fin = cm + (lastT % 3)*1536;
    for (int j = tid; j < NP; j += 1024)
        uvb[j] = -(funkey(fin[j]) + KADD);
}

// S = (4/1500) * sum_b,i (xnrm + ynrm - fs - u)
__global__ void k_final(const float* __restrict__ fs, const float* __restrict__ u,
                        const float* __restrict__ xnrm, const float* __restrict__ ynrm,
                        float* __restrict__ out){
    __shared__ double red[256];
    double s = 0.0;
    for (int t = threadIdx.x; t < NB*NP; t += 256){
        int b = t / NP, i = t - b*NP; int o = b*VSZ + i;
        s += (double)xnrm[o] + (double)ynrm[o] - (double)fs[o] - (double)u[o];
    }
    red[threadIdx.x] = s; __syncthreads();
    for (int w = 128; w > 0; w >>= 1){
        if (threadIdx.x < w) red[threadIdx.x] += red[threadIdx.x + w];
        __syncthreads();
    }
    if (threadIdx.x == 0) out[0] = (float)(red[0] * (4.0/1500.0));
}

extern "C" void kernel_launch(void* const* d_in, const int* in_sizes, int n_in,
                              void* d_out, int out_size, void* d_ws, size_t ws_size,
                              hipStream_t stream) {
    const float* x = (const float*)d_in[0];
    const float* y = (const float*)d_in[1];
    float* out = (float*)d_out;

    __half* pxh = (__half*)d_ws;
    __half* pyh = pxh + (size_t)NB*NP*DP;
    float* csx = (float*)(pyh + (size_t)NB*NP*DP);
    float* csy = csx + NB*DD;
    float* fs  = csy + NB*DD;
    float* uv  = fs + NB*VSZ;
    float* xnrm = uv + NB*VSZ;
    float* ynrm = xnrm + NB*VSZ;
    int* bars  = (int*)(ynrm + NB*VSZ);                // 12*64 ints
    int* flags = bars + 12*64;                         // 12*64 ints
    unsigned* cmin = (unsigned*)(flags + 12*64);       // 4*3*1536 uints
    float* partial = (float*)(cmin + 4*3*1536);        // NCH*NB*2*DD floats
    float* smallEnd = partial + (size_t)NCH*NB*2*DD;
    size_t pOff = (((size_t)((char*)smallEnd - (char*)d_ws)) + 255) & ~(size_t)255;
    __half* P = (__half*)((char*)d_ws + pOff);

    int nzero = (int)(((float*)(flags + 12*64)) - csx);
    int nkeys = 4*3*1536;
    k_init<<<(nzero + nkeys + 255)/256, 256, 0, stream>>>(csx, nzero, cmin, nkeys);

    k_colsum_p1<<<dim3(NCH, NB, 2), 256, 0, stream>>>(x, y, partial);
    k_colsum_p2<<<10, 256, 0, stream>>>(partial, csx, csy);

    k_normrow<<<3000, 256, 0, stream>>>(x, y, csx, csy, pxh, pyh, xnrm, uv, ynrm, cmin);

    k_gemm_mfma<<<dim3(24, 12, NB), 256, 0, stream>>>(pxh, pyh, P);

    k_sink<<<4*OTB, 1024, 0, stream>>>(P, fs, uv, bars, flags, cmin);

    k_final<<<1, 256, 0, stream>>>(fs, uv, xnrm, ynrm, out);
}

// Round 26
// 86.411 us; speedup vs baseline: 1.3675x; 1.3675x over previous
//
// v21 — v19 GEMM restored (128x128); k_init folded into colsum_p1 (rc==NCH blocks);
// k_final folded into k_sink (per-group partial in double + done-counter, fixed-order
// sum => deterministic). 5 launches instead of 7. Base: v19 (best: 114.2).
#include <hip/hip_runtime.h>
#include <hip/hip_fp16.h>

#define NP 1500
#define DD 300
#define DP 320
#define VSZ 1536
#define NB 4
#define TILE 16384
#define TSZ (1536*1536)
#define OTB 16              // blocks per OT group
#define NCH 125             // colsum chunks (12 rows each)
#define KADD 1.8283051e-8f
#define PADVAL (-60000.0f)
#define SCALE 256.0f
#define SCALE2INV (1.0f/65536.0f)
#define FTHR 1e-8f

typedef _Float16 f16x8 __attribute__((ext_vector_type(8)));
typedef float f32x4 __attribute__((ext_vector_type(4)));

__device__ __forceinline__ unsigned fkey(float f){
    unsigned b = __float_as_uint(f);
    return (b & 0x80000000u) ? ~b : (b | 0x80000000u);
}
__device__ __forceinline__ float funkey(unsigned k){
    unsigned b = (k & 0x80000000u) ? (k & 0x7FFFFFFFu) : ~k;
    return __uint_as_float(b);
}

// ---- colsum p1 (125 chunks x 12 rows) + init fold (rc==NCH blocks) ----
__global__ __launch_bounds__(256) void k_colsum_p1(const float* __restrict__ x, const float* __restrict__ y,
                                                   float* __restrict__ partial,
                                                   int* __restrict__ barsflags,   // bars..flags: 1536 ints + done(2) + partS(4 dbl)
                                                   unsigned* __restrict__ cmin){
    int rc = blockIdx.x, b = blockIdx.y, src = blockIdx.z;
    int tid = threadIdx.x;
    if (rc == NCH){
        int idx = (b*2 + src)*256 + tid;   // 0..2047
        if (idx < 1536 + 2 + 8) barsflags[idx] = 0;          // bars, flags, done, partS(=0 bits)
        for (int k = idx; k < 4*3*1536; k += 2048) cmin[k] = 0xFFFFFFFFu;
        return;
    }
    const float* in = (src ? y : x) + ((size_t)b*NP + rc*12)*DD;
    float s0 = 0.f, s1 = 0.f;
    #pragma unroll
    for (int r = 0; r < 12; ++r){
        float v0 = in[r*DD + tid];
        s0 = fmaf(v0, v0, s0);
        if (tid < 44){
            float v1 = in[r*DD + 256 + tid];
            s1 = fmaf(v1, v1, s1);
        }
    }
    float* po = partial + (((size_t)rc*NB + b)*2 + src)*DD;
    po[tid] = s0;
    if (tid < 44) po[256 + tid] = s1;
}

__global__ void k_colsum_p2(const float* __restrict__ partial,
                            float* __restrict__ csx, float* __restrict__ csy){
    int idx = blockIdx.x*256 + threadIdx.x;
    if (idx >= NB*2*DD) return;
    int c = idx % DD; int t = idx / DD; int src = t & 1; int b = t >> 1;
    float s = 0.f;
    for (int rc = 0; rc < NCH; ++rc)
        s += partial[(((size_t)rc*NB + b)*2 + src)*DD + c];
    (src ? csy : csx)[b*DD + c] = s;
}

// ---- normalize + row-norm init; side1 seeds OT cmin buffer 2 with fkey(-(ynrm+KADD)) ----
__global__ __launch_bounds__(256) void k_normrow(const float* __restrict__ x, const float* __restrict__ y,
        const float* __restrict__ csx, const float* __restrict__ csy,
        __half* __restrict__ pxh, __half* __restrict__ pyh,
        float* __restrict__ xnrm, float* __restrict__ uvv, float* __restrict__ ynrm,
        unsigned* __restrict__ cmin){
    int gw = ((int)blockIdx.x*256 + threadIdx.x) >> 6;
    int lane = threadIdx.x & 63;
    int src = (gw >= NB*NP) ? 1 : 0;
    int rem = gw - src*NB*NP;
    int b = rem / NP, i = rem - b*NP;
    const float* in = (src ? y : x) + ((size_t)b*NP + i)*DD;
    const float* cs = (src ? csy : csx) + b*DD;
    __half* oph = (src ? pyh : pxh) + ((size_t)b*NP + i)*DP;
    float s = 0.f;
    #pragma unroll
    for (int it = 0; it < 5; ++it){
        int c = lane + it*64;
        float vu = 0.f, hv = 0.f;
        if (c < DD){
            float u = in[c];
            vu = u*u / cs[c];
            hv = vu * SCALE;
        }
        oph[c] = __float2half(hv);
        s = fmaf(vu, vu, s);
    }
    #pragma unroll
    for (int o2 = 1; o2 < 64; o2 <<= 1) s += __shfl_xor(s, o2, 64);
    if (lane == 0){
        float val = 0.5f * s;
        int o = b*VSZ + i;
        if (src){
            uvv[o] = val; ynrm[o] = val;
            cmin[(b*3 + 2)*1536 + i] = fkey(-(val + KADD));
        } else {
            xnrm[o] = val;
        }
    }
}

// ---- MFMA GEMM: kind0 only, 128x128 tiles (12x12xNB), BK=64, prefetch (v19) ----
__global__ __launch_bounds__(256) void k_gemm_mfma(const __half* __restrict__ pxh,
                                                   const __half* __restrict__ pyh,
                                                   __half* __restrict__ P){
    int b = blockIdx.z;
    int bx = blockIdx.x, by = blockIdx.y;
    const __half* A = pxh + (size_t)b*NP*DP;
    const __half* B = pyh + (size_t)b*NP*DP;

    __shared__ __align__(16) char smem[128*136*2];
    char* ldsA = smem;
    char* ldsB = smem + 16384;
    __half* ldsO = (__half*)smem;

    int tid = threadIdx.x;
    int row0 = bx*128, col0 = by*128;
    int lane = tid & 63;
    int w = tid >> 6;
    int wm = (w >> 1)*64, wn = (w & 1)*64;
    int g8 = tid & 7, rw = tid >> 3;
    int lr = lane & 15, cq = lane >> 4;

    f32x4 acc[4][4];
    #pragma unroll
    for (int mi = 0; mi < 4; ++mi)
        #pragma unroll
        for (int ni = 0; ni < 4; ++ni)
            acc[mi][ni] = (f32x4){0.f, 0.f, 0.f, 0.f};

    uint4 va[4], vb[4];
    #pragma unroll
    for (int is = 0; is < 4; ++is){
        int r = rw + is*32;
        int ar = row0 + r; if (ar > NP-1) ar = NP-1;
        int br = col0 + r; if (br > NP-1) br = NP-1;
        va[is] = *(const uint4*)(A + (size_t)ar*DP + g8*8);
        vb[is] = *(const uint4*)(B + (size_t)br*DP + g8*8);
    }
    #pragma unroll
    for (int ks = 0; ks < 5; ++ks){
        if (ks) __syncthreads();
        #pragma unroll
        for (int is = 0; is < 4; ++is){
            int r = rw + is*32;
            int pc = g8 ^ (r & 7);
            *(uint4*)(ldsA + r*128 + pc*16) = va[is];
            *(uint4*)(ldsB + r*128 + pc*16) = vb[is];
        }
        __syncthreads();
        if (ks < 4){
            int k0 = (ks + 1)*64;
            #pragma unroll
            for (int is = 0; is < 4; ++is){
                int r = rw + is*32;
                int ar = row0 + r; if (ar > NP-1) ar = NP-1;
                int br = col0 + r; if (br > NP-1) br = NP-1;
                va[is] = *(const uint4*)(A + (size_t)ar*DP + k0 + g8*8);
                vb[is] = *(const uint4*)(B + (size_t)br*DP + k0 + g8*8);
            }
        }
        f16x8 av[2][4], bv[2][4];
        #pragma unroll
        for (int ksl = 0; ksl < 2; ++ksl){
            int lc = ksl*4 + cq;
            int pc = (lc ^ (lr & 7))*16;
            #pragma unroll
            for (int mi = 0; mi < 4; ++mi)
                av[ksl][mi] = *(const f16x8*)(ldsA + (wm + mi*16 + lr)*128 + pc);
            #pragma unroll
            for (int ni = 0; ni < 4; ++ni)
                bv[ksl][ni] = *(const f16x8*)(ldsB + (wn + ni*16 + lr)*128 + pc);
        }
        #pragma unroll
        for (int ksl = 0; ksl < 2; ++ksl)
            #pragma unroll
            for (int mi = 0; mi < 4; ++mi)
                #pragma unroll
                for (int ni = 0; ni < 4; ++ni)
                    acc[mi][ni] = __builtin_amdgcn_mfma_f32_16x16x32_f16(av[ksl][mi], bv[ksl][ni], acc[mi][ni], 0, 0, 0);
    }

    int cqe = lane >> 4;
    __syncthreads();
    #pragma unroll
    for (int mi = 0; mi < 4; ++mi)
        #pragma unroll
        for (int ni = 0; ni < 4; ++ni){
            int lcol = wn + ni*16 + lr;
            bool colok = (col0 + lcol) < NP;
            #pragma unroll
            for (int v = 0; v < 4; ++v){
                int lrow = wm + mi*16 + cqe*4 + v;
                bool rowok = (row0 + lrow) < NP;
                ldsO[lrow*136 + lcol] = __float2half((colok && rowok) ? acc[mi][ni][v]*SCALE2INV : PADVAL);
            }
        }
    __syncthreads();
    {
        __half* tileD = P + (size_t)(b*4 + 0)*TSZ + ((size_t)bx*12 + by)*TILE;
        #pragma unroll
        for (int it = 0; it < 8; ++it){
            int e = it*256 + tid;
            int r = e >> 4, q = e & 15;
            *(uint4*)(tileD + r*128 + q*8) = *(const uint4*)(ldsO + r*136 + q*8);
        }
    }
}

// ---- persistent Sinkhorn: 4 OT groups x 16 blocks (fused colmin) + fused final ----
__device__ __forceinline__ void groupbar(int* slot, int gsz){
    __syncthreads();
    if (threadIdx.x == 0){
        __hip_atomic_fetch_add(slot, 1, __ATOMIC_RELEASE, __HIP_MEMORY_SCOPE_AGENT);
        while (__hip_atomic_load(slot, __ATOMIC_ACQUIRE, __HIP_MEMORY_SCOPE_AGENT) < gsz)
            __builtin_amdgcn_s_sleep(1);
    }
    __syncthreads();
}

#define ROWPTR(PK, i) ((PK) + (size_t)((i) >> 7)*12*TILE + (size_t)((i) & 127)*128)

__global__ __launch_bounds__(1024, 1) void k_sink(const __half* __restrict__ P,
        float* __restrict__ fs, float* __restrict__ uvv,
        const float* __restrict__ xnrm, const float* __restrict__ ynrm,
        int* __restrict__ bars, int* __restrict__ flags,
        unsigned* __restrict__ cmin,
        int* __restrict__ done, double* __restrict__ partS,
        float* __restrict__ out){
    int tid = threadIdx.x;
    int lane = tid & 63;
    int wid = tid >> 6;
    int blk = (int)blockIdx.x;
    __shared__ int s_ch;
    __shared__ unsigned lmin[1536];
    __shared__ double red[1024];

    int b = blk / OTB, lb = blk - b*OTB;
    int gw = lb*16 + wid;
    const int NWV = OTB*16;     // 256 waves
    int* gbarp  = bars + b*64;
    int* gflagp = flags + b*64;
    const __half* P0 = P + (size_t)(b*4 + 0)*TSZ;
    float* fsb = fs + b*VSZ;
    float* uvb = uvv + b*VSZ;
    unsigned* cm = cmin + b*3*1536;

    int colb[3];
    #pragma unroll
    for (int it = 0; it < 3; ++it){
        int c = lane + it*64;
        colb[it] = ((c >> 4) << 7) + ((c & 15) << 3);
    }

    int lastT = 0;
    for (int t = 0; t < 30; ++t){
        unsigned* rdbuf = cm + ((t + 2) % 3)*1536;
        unsigned* wrbuf = cm + (t % 3)*1536;
        unsigned* rsbuf = cm + ((t + 1) % 3)*1536;
        if (tid == 0) s_ch = 0;
        for (int idx = tid; idx < 1536; idx += 1024) lmin[idx] = 0xFFFFFFFFu;
        float Au[3][8];
        #pragma unroll
        for (int it = 0; it < 3; ++it){
            uint4 k0 = *(const uint4*)(rdbuf + colb[it]);
            uint4 k1 = *(const uint4*)(rdbuf + colb[it] + 4);
            unsigned kk[8] = {k0.x, k0.y, k0.z, k0.w, k1.x, k1.y, k1.z, k1.w};
            #pragma unroll
            for (int e = 0; e < 8; ++e){
                int col = colb[it] + e;
                Au[it][e] = (col < NP) ? (-(funkey(kk[e]) + KADD)) : 3.0e38f;
            }
        }
        __syncthreads();
        float amin[3][8];
        #pragma unroll
        for (int it = 0; it < 3; ++it)
            #pragma unroll
            for (int e = 0; e < 8; ++e) amin[it][e] = 3.0e38f;
        int ch = 0;
        for (int i = gw; i < NP; i += NWV){
            const __half* rowb = ROWPTR(P0, i);
            uint4 pk[3];
            #pragma unroll
            for (int it = 0; it < 3; ++it){
                int c = lane + it*64, tt = c >> 4, q = c & 15;
                pk[it] = *(const uint4*)(rowb + (size_t)tt*TILE + q*8);
            }
            float cf[3][8];
            float m = 3.0e38f;
            #pragma unroll
            for (int it = 0; it < 3; ++it){
                float2 c0 = __half22float2(*(const __half2*)&pk[it].x);
                float2 c1 = __half22float2(*(const __half2*)&pk[it].y);
                float2 c2 = __half22float2(*(const __half2*)&pk[it].z);
                float2 c3 = __half22float2(*(const __half2*)&pk[it].w);
                cf[it][0] = c0.x; cf[it][1] = c0.y; cf[it][2] = c1.x; cf[it][3] = c1.y;
                cf[it][4] = c2.x; cf[it][5] = c2.y; cf[it][6] = c3.x; cf[it][7] = c3.y;
                #pragma unroll
                for (int e = 0; e < 8; ++e) m = fminf(m, Au[it][e] - cf[it][e]);
            }
            #pragma unroll
            for (int o = 1; o < 64; o <<= 1) m = fminf(m, __shfl_xor(m, o, 64));
            float nv = -(m + KADD);
            if (lane == 0){
                if (fabsf(nv - fsb[i]) > FTHR) ch = 1;
                fsb[i] = nv;
            }
            #pragma unroll
            for (int it = 0; it < 3; ++it)
                #pragma unroll
                for (int e = 0; e < 8; ++e)
                    amin[it][e] = fminf(amin[it][e], nv - cf[it][e]);
        }
        if (ch) s_ch = 1;
        #pragma unroll
        for (int it = 0; it < 3; ++it)
            #pragma unroll
            for (int e = 0; e < 8; ++e)
                atomicMin(&lmin[colb[it] + e], fkey(amin[it][e]));
        __syncthreads();
        for (int idx = tid; idx < 1536; idx += 1024)
            atomicMin(&wrbuf[idx], lmin[idx]);
        if (tid < 96) rsbuf[lb*96 + tid] = 0xFFFFFFFFu;
        if (tid == 0 && s_ch) atomicOr(&gflagp[t], 1);
        groupbar(&gbarp[t], OTB);
        lastT = t;
        int fA = __hip_atomic_load(&gflagp[t], __ATOMIC_RELAXED, __HIP_MEMORY_SCOPE_AGENT);
        if (fA == 0) break;
    }
    unsigned* fin = cm + (lastT % 3)*1536;
    for (int j = tid; j < NP; j += 1024)
        uvb[j] = -(funkey(fin[j]) + KADD);

    // ---- fused final: lb==0 computes batch partial; 4th arrival sums (fixed order) ----
    if (lb == 0){
        const float* xb = xnrm + b*VSZ;
        const float* yb = ynrm + b*VSZ;
        double s = 0.0;
        for (int i = tid; i < NP; i += 1024)
            s += (double)xb[i] + (double)yb[i] - (double)fsb[i] - (double)uvb[i];
        __syncthreads();
        red[tid] = s; __syncthreads();
        for (int w2 = 512; w2 > 0; w2 >>= 1){
            if (tid < w2) red[tid] += red[tid + w2];
            __syncthreads();
        }
        if (tid == 0){
            partS[b] = red[0];
            int old = __hip_atomic_fetch_add(done, 1, __ATOMIC_ACQ_REL, __HIP_MEMORY_SCOPE_AGENT);
            if (old == 3)
                out[0] = (float)((partS[0] + partS[1] + partS[2] + partS[3]) * (4.0/1500.0));
        }
    }
}

extern "C" void kernel_launch(void* const* d_in, const int* in_sizes, int n_in,
                              void* d_out, int out_size, void* d_ws, size_t ws_size,
                              hipStream_t stream) {
    const float* x = (const float*)d_in[0];
    const float* y = (const float*)d_in[1];
    float* out = (float*)d_out;

    __half* pxh = (__half*)d_ws;
    __half* pyh = pxh + (size_t)NB*NP*DP;
    float* csx = (float*)(pyh + (size_t)NB*NP*DP);
    float* csy = csx + NB*DD;
    float* fs  = csy + NB*DD;
    float* uv  = fs + NB*VSZ;
    float* xnrm = uv + NB*VSZ;
    float* ynrm = xnrm + NB*VSZ;
    int* bars  = (int*)(ynrm + NB*VSZ);                // 12*64 ints (bars.. then flags)
    int* flags = bars + 12*64;
    int* done  = flags + 12*64;                        // 2 ints (8B aligned)
    double* partS = (double*)(done + 2);               // 4 doubles
    unsigned* cmin = (unsigned*)(partS + 4);           // 4*3*1536 uints
    float* partial = (float*)(cmin + 4*3*1536);        // NCH*NB*2*DD floats
    float* smallEnd = partial + (size_t)NCH*NB*2*DD;
    size_t pOff = (((size_t)((char*)smallEnd - (char*)d_ws)) + 255) & ~(size_t)255;
    __half* P = (__half*)((char*)d_ws + pOff);

    k_colsum_p1<<<dim3(NCH + 1, NB, 2), 256, 0, stream>>>(x, y, partial, bars, cmin);
    k_colsum_p2<<<10, 256, 0, stream>>>(partial, csx, csy);

    k_normrow<<<3000, 256, 0, stream>>>(x, y, csx, csy, pxh, pyh, xnrm, uv, ynrm, cmin);

    k_gemm_mfma<<<dim3(12, 12, NB), 256, 0, stream>>>(pxh, pyh, P);

    k_sink<<<4*OTB, 1024, 0, stream>>>(P, fs, uv, xnrm, ynrm, bars, flags, cmin, done, partS, out);
}

// Round 27
// 85.254 us; speedup vs baseline: 1.3861x; 1.0136x over previous
//
// v22 — v21 with XCD-aware GEMM block mapping: flat 576-block grid, xcd=n&7 keyed to
// batch (b=xcd&3) so each XCD's L2 holds exactly one batch's A+B panels (1.92MB < 4MB;
// was 7.7MB thrash). Everything else identical to v21 (best: 86.4).
#include <hip/hip_runtime.h>
#include <hip/hip_fp16.h>

#define NP 1500
#define DD 300
#define DP 320
#define VSZ 1536
#define NB 4
#define TILE 16384
#define TSZ (1536*1536)
#define OTB 16              // blocks per OT group
#define NCH 125             // colsum chunks (12 rows each)
#define KADD 1.8283051e-8f
#define PADVAL (-60000.0f)
#define SCALE 256.0f
#define SCALE2INV (1.0f/65536.0f)
#define FTHR 1e-8f

typedef _Float16 f16x8 __attribute__((ext_vector_type(8)));
typedef float f32x4 __attribute__((ext_vector_type(4)));

__device__ __forceinline__ unsigned fkey(float f){
    unsigned b = __float_as_uint(f);
    return (b & 0x80000000u) ? ~b : (b | 0x80000000u);
}
__device__ __forceinline__ float funkey(unsigned k){
    unsigned b = (k & 0x80000000u) ? (k & 0x7FFFFFFFu) : ~k;
    return __uint_as_float(b);
}

// ---- colsum p1 (125 chunks x 12 rows) + init fold (rc==NCH blocks) ----
__global__ __launch_bounds__(256) void k_colsum_p1(const float* __restrict__ x, const float* __restrict__ y,
                                                   float* __restrict__ partial,
                                                   int* __restrict__ barsflags,
                                                   unsigned* __restrict__ cmin){
    int rc = blockIdx.x, b = blockIdx.y, src = blockIdx.z;
    int tid = threadIdx.x;
    if (rc == NCH){
        int idx = (b*2 + src)*256 + tid;   // 0..2047
        if (idx < 1536 + 2 + 8) barsflags[idx] = 0;
        for (int k = idx; k < 4*3*1536; k += 2048) cmin[k] = 0xFFFFFFFFu;
        return;
    }
    const float* in = (src ? y : x) + ((size_t)b*NP + rc*12)*DD;
    float s0 = 0.f, s1 = 0.f;
    #pragma unroll
    for (int r = 0; r < 12; ++r){
        float v0 = in[r*DD + tid];
        s0 = fmaf(v0, v0, s0);
        if (tid < 44){
            float v1 = in[r*DD + 256 + tid];
            s1 = fmaf(v1, v1, s1);
        }
    }
    float* po = partial + (((size_t)rc*NB + b)*2 + src)*DD;
    po[tid] = s0;
    if (tid < 44) po[256 + tid] = s1;
}

__global__ void k_colsum_p2(const float* __restrict__ partial,
                            float* __restrict__ csx, float* __restrict__ csy){
    int idx = blockIdx.x*256 + threadIdx.x;
    if (idx >= NB*2*DD) return;
    int c = idx % DD; int t = idx / DD; int src = t & 1; int b = t >> 1;
    float s = 0.f;
    for (int rc = 0; rc < NCH; ++rc)
        s += partial[(((size_t)rc*NB + b)*2 + src)*DD + c];
    (src ? csy : csx)[b*DD + c] = s;
}

// ---- normalize + row-norm init; side1 seeds OT cmin buffer 2 with fkey(-(ynrm+KADD)) ----
__global__ __launch_bounds__(256) void k_normrow(const float* __restrict__ x, const float* __restrict__ y,
        const float* __restrict__ csx, const float* __restrict__ csy,
        __half* __restrict__ pxh, __half* __restrict__ pyh,
        float* __restrict__ xnrm, float* __restrict__ uvv, float* __restrict__ ynrm,
        unsigned* __restrict__ cmin){
    int gw = ((int)blockIdx.x*256 + threadIdx.x) >> 6;
    int lane = threadIdx.x & 63;
    int src = (gw >= NB*NP) ? 1 : 0;
    int rem = gw - src*NB*NP;
    int b = rem / NP, i = rem - b*NP;
    const float* in = (src ? y : x) + ((size_t)b*NP + i)*DD;
    const float* cs = (src ? csy : csx) + b*DD;
    __half* oph = (src ? pyh : pxh) + ((size_t)b*NP + i)*DP;
    float s = 0.f;
    #pragma unroll
    for (int it = 0; it < 5; ++it){
        int c = lane + it*64;
        float vu = 0.f, hv = 0.f;
        if (c < DD){
            float u = in[c];
            vu = u*u / cs[c];
            hv = vu * SCALE;
        }
        oph[c] = __float2half(hv);
        s = fmaf(vu, vu, s);
    }
    #pragma unroll
    for (int o2 = 1; o2 < 64; o2 <<= 1) s += __shfl_xor(s, o2, 64);
    if (lane == 0){
        float val = 0.5f * s;
        int o = b*VSZ + i;
        if (src){
            uvv[o] = val; ynrm[o] = val;
            cmin[(b*3 + 2)*1536 + i] = fkey(-(val + KADD));
        } else {
            xnrm[o] = val;
        }
    }
}

// ---- MFMA GEMM: kind0 only, 128x128 tiles, flat 576-block grid with XCD-batch keying ----
__global__ __launch_bounds__(256) void k_gemm_mfma(const __half* __restrict__ pxh,
                                                   const __half* __restrict__ pyh,
                                                   __half* __restrict__ P){
    int n = (int)blockIdx.x;
    int xcd = n & 7;                 // assumed round-robin XCD mapping (perf heuristic)
    int b = xcd & 3;                 // one batch per XCD -> L2-resident panels
    int t = (xcd >> 2)*72 + (n >> 3);  // 0..143 within batch
    int bx = t / 12, by = t - bx*12;
    const __half* A = pxh + (size_t)b*NP*DP;
    const __half* B = pyh + (size_t)b*NP*DP;

    __shared__ __align__(16) char smem[128*136*2];
    char* ldsA = smem;
    char* ldsB = smem + 16384;
    __half* ldsO = (__half*)smem;

    int tid = threadIdx.x;
    int row0 = bx*128, col0 = by*128;
    int lane = tid & 63;
    int w = tid >> 6;
    int wm = (w >> 1)*64, wn = (w & 1)*64;
    int g8 = tid & 7, rw = tid >> 3;
    int lr = lane & 15, cq = lane >> 4;

    f32x4 acc[4][4];
    #pragma unroll
    for (int mi = 0; mi < 4; ++mi)
        #pragma unroll
        for (int ni = 0; ni < 4; ++ni)
            acc[mi][ni] = (f32x4){0.f, 0.f, 0.f, 0.f};

    uint4 va[4], vb[4];
    #pragma unroll
    for (int is = 0; is < 4; ++is){
        int r = rw + is*32;
        int ar = row0 + r; if (ar > NP-1) ar = NP-1;
        int br = col0 + r; if (br > NP-1) br = NP-1;
        va[is] = *(const uint4*)(A + (size_t)ar*DP + g8*8);
        vb[is] = *(const uint4*)(B + (size_t)br*DP + g8*8);
    }
    #pragma unroll
    for (int ks = 0; ks < 5; ++ks){
        if (ks) __syncthreads();
        #pragma unroll
        for (int is = 0; is < 4; ++is){
            int r = rw + is*32;
            int pc = g8 ^ (r & 7);
            *(uint4*)(ldsA + r*128 + pc*16) = va[is];
            *(uint4*)(ldsB + r*128 + pc*16) = vb[is];
        }
        __syncthreads();
        if (ks < 4){
            int k0 = (ks + 1)*64;
            #pragma unroll
            for (int is = 0; is < 4; ++is){
                int r = rw + is*32;
                int ar = row0 + r; if (ar > NP-1) ar = NP-1;
                int br = col0 + r; if (br > NP-1) br = NP-1;
                va[is] = *(const uint4*)(A + (size_t)ar*DP + k0 + g8*8);
                vb[is] = *(const uint4*)(B + (size_t)br*DP + k0 + g8*8);
            }
        }
        f16x8 av[2][4], bv[2][4];
        #pragma unroll
        for (int ksl = 0; ksl < 2; ++ksl){
            int lc = ksl*4 + cq;
            int pc = (lc ^ (lr & 7))*16;
            #pragma unroll
            for (int mi = 0; mi < 4; ++mi)
                av[ksl][mi] = *(const f16x8*)(ldsA + (wm + mi*16 + lr)*128 + pc);
            #pragma unroll
            for (int ni = 0; ni < 4; ++ni)
                bv[ksl][ni] = *(const f16x8*)(ldsB + (wn + ni*16 + lr)*128 + pc);
        }
        #pragma unroll
        for (int ksl = 0; ksl < 2; ++ksl)
            #pragma unroll
            for (int mi = 0; mi < 4; ++mi)
                #pragma unroll
                for (int ni = 0; ni < 4; ++ni)
                    acc[mi][ni] = __builtin_amdgcn_mfma_f32_16x16x32_f16(av[ksl][mi], bv[ksl][ni], acc[mi][ni], 0, 0, 0);
    }

    int cqe = lane >> 4;
    __syncthreads();
    #pragma unroll
    for (int mi = 0; mi < 4; ++mi)
        #pragma unroll
        for (int ni = 0; ni < 4; ++ni){
            int lcol = wn + ni*16 + lr;
            bool colok = (col0 + lcol) < NP;
            #pragma unroll
            for (int v = 0; v < 4; ++v){
                int lrow = wm + mi*16 + cqe*4 + v;
                bool rowok = (row0 + lrow) < NP;
                ldsO[lrow*136 + lcol] = __float2half((colok && rowok) ? acc[mi][ni][v]*SCALE2INV : PADVAL);
            }
        }
    __syncthreads();
    {
        __half* tileD = P + (size_t)(b*4 + 0)*TSZ + ((size_t)bx*12 + by)*TILE;
        #pragma unroll
        for (int it = 0; it < 8; ++it){
            int e = it*256 + tid;
            int r = e >> 4, q = e & 15;
            *(uint4*)(tileD + r*128 + q*8) = *(const uint4*)(ldsO + r*136 + q*8);
        }
    }
}

// ---- persistent Sinkhorn: 4 OT groups x 16 blocks (fused colmin) + fused final ----
__device__ __forceinline__ void groupbar(int* slot, int gsz){
    __syncthreads();
    if (threadIdx.x == 0){
        __hip_atomic_fetch_add(slot, 1, __ATOMIC_RELEASE, __HIP_MEMORY_SCOPE_AGENT);
        while (__hip_atomic_load(slot, __ATOMIC_ACQUIRE, __HIP_MEMORY_SCOPE_AGENT) < gsz)
            __builtin_amdgcn_s_sleep(1);
    }
    __syncthreads();
}

#define ROWPTR(PK, i) ((PK) + (size_t)((i) >> 7)*12*TILE + (size_t)((i) & 127)*128)

__global__ __launch_bounds__(1024, 1) void k_sink(const __half* __restrict__ P,
        float* __restrict__ fs, float* __restrict__ uvv,
        const float* __restrict__ xnrm, const float* __restrict__ ynrm,
        int* __restrict__ bars, int* __restrict__ flags,
        unsigned* __restrict__ cmin,
        int* __restrict__ done, double* __restrict__ partS,
        float* __restrict__ out){
    int tid = threadIdx.x;
    int lane = tid & 63;
    int wid = tid >> 6;
    int blk = (int)blockIdx.x;
    __shared__ int s_ch;
    __shared__ unsigned lmin[1536];
    __shared__ double red[1024];

    int b = blk / OTB, lb = blk - b*OTB;
    int gw = lb*16 + wid;
    const int NWV = OTB*16;     // 256 waves
    int* gbarp  = bars + b*64;
    int* gflagp = flags + b*64;
    const __half* P0 = P + (size_t)(b*4 + 0)*TSZ;
    float* fsb = fs + b*VSZ;
    float* uvb = uvv + b*VSZ;
    unsigned* cm = cmin + b*3*1536;

    int colb[3];
    #pragma unroll
    for (int it = 0; it < 3; ++it){
        int c = lane + it*64;
        colb[it] = ((c >> 4) << 7) + ((c & 15) << 3);
    }

    int lastT = 0;
    for (int t = 0; t < 30; ++t){
        unsigned* rdbuf = cm + ((t + 2) % 3)*1536;
        unsigned* wrbuf = cm + (t % 3)*1536;
        unsigned* rsbuf = cm + ((t + 1) % 3)*1536;
        if (tid == 0) s_ch = 0;
        for (int idx = tid; idx < 1536; idx += 1024) lmin[idx] = 0xFFFFFFFFu;
        float Au[3][8];
        #pragma unroll
        for (int it = 0; it < 3; ++it){
            uint4 k0 = *(const uint4*)(rdbuf + colb[it]);
            uint4 k1 = *(const uint4*)(rdbuf + colb[it] + 4);
            unsigned kk[8] = {k0.x, k0.y, k0.z, k0.w, k1.x, k1.y, k1.z, k1.w};
            #pragma unroll
            for (int e = 0; e < 8; ++e){
                int col = colb[it] + e;
                Au[it][e] = (col < NP) ? (-(funkey(kk[e]) + KADD)) : 3.0e38f;
            }
        }
        __syncthreads();
        float amin[3][8];
        #pragma unroll
        for (int it = 0; it < 3; ++it)
            #pragma unroll
            for (int e = 0; e < 8; ++e) amin[it][e] = 3.0e38f;
        int ch = 0;
        for (int i = gw; i < NP; i += NWV){
            const __half* rowb = ROWPTR(P0, i);
            uint4 pk[3];
            #pragma unroll
            for (int it = 0; it < 3; ++it){
                int c = lane + it*64, tt = c >> 4, q = c & 15;
                pk[it] = *(const uint4*)(rowb + (size_t)tt*TILE + q*8);
            }
            float cf[3][8];
            float m = 3.0e38f;
            #pragma unroll
            for (int it = 0; it < 3; ++it){
                float2 c0 = __half22float2(*(const __half2*)&pk[it].x);
                float2 c1 = __half22float2(*(const __half2*)&pk[it].y);
                float2 c2 = __half22float2(*(const __half2*)&pk[it].z);
                float2 c3 = __half22float2(*(const __half2*)&pk[it].w);
                cf[it][0] = c0.x; cf[it][1] = c0.y; cf[it][2] = c1.x; cf[it][3] = c1.y;
                cf[it][4] = c2.x; cf[it][5] = c2.y; cf[it][6] = c3.x; cf[it][7] = c3.y;
                #pragma unroll
                for (int e = 0; e < 8; ++e) m = fminf(m, Au[it][e] - cf[it][e]);
            }
            #pragma unroll
            for (int o = 1; o < 64; o <<= 1) m = fminf(m, __shfl_xor(m, o, 64));
            float nv = -(m + KADD);
            if (lane == 0){
                if (fabsf(nv - fsb[i]) > FTHR) ch = 1;
                fsb[i] = nv;
            }
            #pragma unroll
            for (int it = 0; it < 3; ++it)
                #pragma unroll
                for (int e = 0; e < 8; ++e)
                    amin[it][e] = fminf(amin[it][e], nv - cf[it][e]);
        }
        if (ch) s_ch = 1;
        #pragma unroll
        for (int it = 0; it < 3; ++it)
            #pragma unroll
            for (int e = 0; e < 8; ++e)
                atomicMin(&lmin[colb[it] + e], fkey(amin[it][e]));
        __syncthreads();
        for (int idx = tid; idx < 1536; idx += 1024)
            atomicMin(&wrbuf[idx], lmin[idx]);
        if (tid < 96) rsbuf[lb*96 + tid] = 0xFFFFFFFFu;
        if (tid == 0 && s_ch) atomicOr(&gflagp[t], 1);
        groupbar(&gbarp[t], OTB);
        lastT = t;
        int fA = __hip_atomic_load(&gflagp[t], __ATOMIC_RELAXED, __HIP_MEMORY_SCOPE_AGENT);
        if (fA == 0) break;
    }
    unsigned* fin = cm + (lastT % 3)*1536;
    for (int j = tid; j < NP; j += 1024)
        uvb[j] = -(funkey(fin[j]) + KADD);

    // ---- fused final: lb==0 computes batch partial; 4th arrival sums (fixed order) ----
    if (lb == 0){
        const float* xb = xnrm + b*VSZ;
        const float* yb = ynrm + b*VSZ;
        double s = 0.0;
        for (int i = tid; i < NP; i += 1024)
            s += (double)xb[i] + (double)yb[i] - (double)fsb[i] - (double)uvb[i];
        __syncthreads();
        red[tid] = s; __syncthreads();
        for (int w2 = 512; w2 > 0; w2 >>= 1){
            if (tid < w2) red[tid] += red[tid + w2];
            __syncthreads();
        }
        if (tid == 0){
            partS[b] = red[0];
            int old = __hip_atomic_fetch_add(done, 1, __ATOMIC_ACQ_REL, __HIP_MEMORY_SCOPE_AGENT);
            if (old == 3)
                out[0] = (float)((partS[0] + partS[1] + partS[2] + partS[3]) * (4.0/1500.0));
        }
    }
}

extern "C" void kernel_launch(void* const* d_in, const int* in_sizes, int n_in,
                              void* d_out, int out_size, void* d_ws, size_t ws_size,
                              hipStream_t stream) {
    const float* x = (const float*)d_in[0];
    const float* y = (const float*)d_in[1];
    float* out = (float*)d_out;

    __half* pxh = (__half*)d_ws;
    __half* pyh = pxh + (size_t)NB*NP*DP;
    float* csx = (float*)(pyh + (size_t)NB*NP*DP);
    float* csy = csx + NB*DD;
    float* fs  = csy + NB*DD;
    float* uv  = fs + NB*VSZ;
    float* xnrm = uv + NB*VSZ;
    float* ynrm = xnrm + NB*VSZ;
    int* bars  = (int*)(ynrm + NB*VSZ);                // 12*64 ints (bars.. then flags)
    int* flags = bars + 12*64;
    int* done  = flags + 12*64;                        // 2 ints (8B aligned)
    double* partS = (double*)(done + 2);               // 4 doubles
    unsigned* cmin = (unsigned*)(partS + 4);           // 4*3*1536 uints
    float* partial = (float*)(cmin + 4*3*1536);        // NCH*NB*2*DD floats
    float* smallEnd = partial + (size_t)NCH*NB*2*DD;
    size_t pOff = (((size_t)((char*)smallEnd - (char*)d_ws)) + 255) & ~(size_t)255;
    __half* P = (__half*)((char*)d_ws + pOff);

    k_colsum_p1<<<dim3(NCH + 1, NB, 2), 256, 0, stream>>>(x, y, partial, bars, cmin);
    k_colsum_p2<<<10, 256, 0, stream>>>(partial, csx, csy);

    k_normrow<<<3000, 256, 0, stream>>>(x, y, csx, csy, pxh, pyh, xnrm, uv, ynrm, cmin);

    k_gemm_mfma<<<576, 256, 0, stream>>>(pxh, pyh, P);

    k_sink<<<4*OTB, 1024, 0, stream>>>(P, fs, uv, xnrm, ynrm, bars, flags, cmin, done, partS, out);
}

// Round 28
// 63.689 us; speedup vs baseline: 1.8554x; 1.3386x over previous
//
// v23 — GEMM rebuilt with 1024-thread blocks (16 waves, 4x4 wave grid, 32x32/wave),
// same 128x128 tile & 5-step K-loop: 2 blocks/CU = 32 waves/CU (thread-cap occupancy)
// to hide the serial K-chain latency. Everything else identical to v22 (best: 85.25).
#include <hip/hip_runtime.h>
#include <hip/hip_fp16.h>

#define NP 1500
#define DD 300
#define DP 320
#define VSZ 1536
#define NB 4
#define TILE 16384
#define TSZ (1536*1536)
#define OTB 16              // blocks per OT group
#define NCH 125             // colsum chunks (12 rows each)
#define KADD 1.8283051e-8f
#define PADVAL (-60000.0f)
#define SCALE 256.0f
#define SCALE2INV (1.0f/65536.0f)
#define FTHR 1e-8f

typedef _Float16 f16x8 __attribute__((ext_vector_type(8)));
typedef float f32x4 __attribute__((ext_vector_type(4)));

__device__ __forceinline__ unsigned fkey(float f){
    unsigned b = __float_as_uint(f);
    return (b & 0x80000000u) ? ~b : (b | 0x80000000u);
}
__device__ __forceinline__ float funkey(unsigned k){
    unsigned b = (k & 0x80000000u) ? (k & 0x7FFFFFFFu) : ~k;
    return __uint_as_float(b);
}

// ---- colsum p1 (125 chunks x 12 rows) + init fold (rc==NCH blocks) ----
__global__ __launch_bounds__(256) void k_colsum_p1(const float* __restrict__ x, const float* __restrict__ y,
                                                   float* __restrict__ partial,
                                                   int* __restrict__ barsflags,
                                                   unsigned* __restrict__ cmin){
    int rc = blockIdx.x, b = blockIdx.y, src = blockIdx.z;
    int tid = threadIdx.x;
    if (rc == NCH){
        int idx = (b*2 + src)*256 + tid;   // 0..2047
        if (idx < 1536 + 2 + 8) barsflags[idx] = 0;
        for (int k = idx; k < 4*3*1536; k += 2048) cmin[k] = 0xFFFFFFFFu;
        return;
    }
    const float* in = (src ? y : x) + ((size_t)b*NP + rc*12)*DD;
    float s0 = 0.f, s1 = 0.f;
    #pragma unroll
    for (int r = 0; r < 12; ++r){
        float v0 = in[r*DD + tid];
        s0 = fmaf(v0, v0, s0);
        if (tid < 44){
            float v1 = in[r*DD + 256 + tid];
            s1 = fmaf(v1, v1, s1);
        }
    }
    float* po = partial + (((size_t)rc*NB + b)*2 + src)*DD;
    po[tid] = s0;
    if (tid < 44) po[256 + tid] = s1;
}

__global__ void k_colsum_p2(const float* __restrict__ partial,
                            float* __restrict__ csx, float* __restrict__ csy){
    int idx = blockIdx.x*256 + threadIdx.x;
    if (idx >= NB*2*DD) return;
    int c = idx % DD; int t = idx / DD; int src = t & 1; int b = t >> 1;
    float s = 0.f;
    for (int rc = 0; rc < NCH; ++rc)
        s += partial[(((size_t)rc*NB + b)*2 + src)*DD + c];
    (src ? csy : csx)[b*DD + c] = s;
}

// ---- normalize + row-norm init; side1 seeds OT cmin buffer 2 with fkey(-(ynrm+KADD)) ----
__global__ __launch_bounds__(256) void k_normrow(const float* __restrict__ x, const float* __restrict__ y,
        const float* __restrict__ csx, const float* __restrict__ csy,
        __half* __restrict__ pxh, __half* __restrict__ pyh,
        float* __restrict__ xnrm, float* __restrict__ uvv, float* __restrict__ ynrm,
        unsigned* __restrict__ cmin){
    int gw = ((int)blockIdx.x*256 + threadIdx.x) >> 6;
    int lane = threadIdx.x & 63;
    int src = (gw >= NB*NP) ? 1 : 0;
    int rem = gw - src*NB*NP;
    int b = rem / NP, i = rem - b*NP;
    const float* in = (src ? y : x) + ((size_t)b*NP + i)*DD;
    const float* cs = (src ? csy : csx) + b*DD;
    __half* oph = (src ? pyh : pxh) + ((size_t)b*NP + i)*DP;
    float s = 0.f;
    #pragma unroll
    for (int it = 0; it < 5; ++it){
        int c = lane + it*64;
        float vu = 0.f, hv = 0.f;
        if (c < DD){
            float u = in[c];
            vu = u*u / cs[c];
            hv = vu * SCALE;
        }
        oph[c] = __float2half(hv);
        s = fmaf(vu, vu, s);
    }
    #pragma unroll
    for (int o2 = 1; o2 < 64; o2 <<= 1) s += __shfl_xor(s, o2, 64);
    if (lane == 0){
        float val = 0.5f * s;
        int o = b*VSZ + i;
        if (src){
            uvv[o] = val; ynrm[o] = val;
            cmin[(b*3 + 2)*1536 + i] = fkey(-(val + KADD));
        } else {
            xnrm[o] = val;
        }
    }
}

// ---- MFMA GEMM: kind0 only, 128x128 tiles, 1024 threads (16 waves, 4x4 wave grid) ----
__global__ __launch_bounds__(1024) void k_gemm_mfma(const __half* __restrict__ pxh,
                                                    const __half* __restrict__ pyh,
                                                    __half* __restrict__ P){
    int n = (int)blockIdx.x;
    int xcd = n & 7;                 // round-robin XCD heuristic
    int b = xcd & 3;
    int t = (xcd >> 2)*72 + (n >> 3);  // 0..143 within batch
    int bx = t / 12, by = t - bx*12;
    const __half* A = pxh + (size_t)b*NP*DP;
    const __half* B = pyh + (size_t)b*NP*DP;

    __shared__ __align__(16) char smem[128*136*2];   // staging 32KB; epilogue 34.8KB overlaid
    char* ldsA = smem;                  // 128 rows x 64 halfs
    char* ldsB = smem + 16384;
    __half* ldsO = (__half*)smem;

    int tid = threadIdx.x;
    int row0 = bx*128, col0 = by*128;
    int lane = tid & 63;
    int w = tid >> 6;                   // 0..15
    int wm = (w >> 2)*32, wn = (w & 3)*32;
    int g8 = tid & 7, rw = tid >> 3;    // 8 chunks x 128 rows
    int lr = lane & 15, cq = lane >> 4;

    f32x4 acc[2][2];
    #pragma unroll
    for (int mi = 0; mi < 2; ++mi)
        #pragma unroll
        for (int ni = 0; ni < 2; ++ni)
            acc[mi][ni] = (f32x4){0.f, 0.f, 0.f, 0.f};

    uint4 va, vb;
    {
        int ar = row0 + rw; if (ar > NP-1) ar = NP-1;
        int br = col0 + rw; if (br > NP-1) br = NP-1;
        va = *(const uint4*)(A + (size_t)ar*DP + g8*8);
        vb = *(const uint4*)(B + (size_t)br*DP + g8*8);
    }
    #pragma unroll
    for (int ks = 0; ks < 5; ++ks){
        if (ks) __syncthreads();
        {
            int pc = g8 ^ (rw & 7);
            *(uint4*)(ldsA + rw*128 + pc*16) = va;
            *(uint4*)(ldsB + rw*128 + pc*16) = vb;
        }
        __syncthreads();
        if (ks < 4){
            int k0 = (ks + 1)*64;
            int ar = row0 + rw; if (ar > NP-1) ar = NP-1;
            int br = col0 + rw; if (br > NP-1) br = NP-1;
            va = *(const uint4*)(A + (size_t)ar*DP + k0 + g8*8);
            vb = *(const uint4*)(B + (size_t)br*DP + k0 + g8*8);
        }
        f16x8 av[2][2], bv[2][2];
        #pragma unroll
        for (int ksl = 0; ksl < 2; ++ksl){
            int lc = ksl*4 + cq;
            int pc = (lc ^ (lr & 7))*16;
            #pragma unroll
            for (int mi = 0; mi < 2; ++mi)
                av[ksl][mi] = *(const f16x8*)(ldsA + (wm + mi*16 + lr)*128 + pc);
            #pragma unroll
            for (int ni = 0; ni < 2; ++ni)
                bv[ksl][ni] = *(const f16x8*)(ldsB + (wn + ni*16 + lr)*128 + pc);
        }
        #pragma unroll
        for (int ksl = 0; ksl < 2; ++ksl)
            #pragma unroll
            for (int mi = 0; mi < 2; ++mi)
                #pragma unroll
                for (int ni = 0; ni < 2; ++ni)
                    acc[mi][ni] = __builtin_amdgcn_mfma_f32_16x16x32_f16(av[ksl][mi], bv[ksl][ni], acc[mi][ni], 0, 0, 0);
    }

    int cqe = lane >> 4;
    __syncthreads();
    #pragma unroll
    for (int mi = 0; mi < 2; ++mi)
        #pragma unroll
        for (int ni = 0; ni < 2; ++ni){
            int lcol = wn + ni*16 + lr;
            bool colok = (col0 + lcol) < NP;
            #pragma unroll
            for (int v = 0; v < 4; ++v){
                int lrow = wm + mi*16 + cqe*4 + v;
                bool rowok = (row0 + lrow) < NP;
                ldsO[lrow*136 + lcol] = __float2half((colok && rowok) ? acc[mi][ni][v]*SCALE2INV : PADVAL);
            }
        }
    __syncthreads();
    {
        __half* tileD = P + (size_t)(b*4 + 0)*TSZ + ((size_t)bx*12 + by)*TILE;
        #pragma unroll
        for (int it = 0; it < 2; ++it){
            int e = it*1024 + tid;
            int r = e >> 4, q = e & 15;
            *(uint4*)(tileD + r*128 + q*8) = *(const uint4*)(ldsO + r*136 + q*8);
        }
    }
}

// ---- persistent Sinkhorn: 4 OT groups x 16 blocks (fused colmin) + fused final ----
__device__ __forceinline__ void groupbar(int* slot, int gsz){
    __syncthreads();
    if (threadIdx.x == 0){
        __hip_atomic_fetch_add(slot, 1, __ATOMIC_RELEASE, __HIP_MEMORY_SCOPE_AGENT);
        while (__hip_atomic_load(slot, __ATOMIC_ACQUIRE, __HIP_MEMORY_SCOPE_AGENT) < gsz)
            __builtin_amdgcn_s_sleep(1);
    }
    __syncthreads();
}

#define ROWPTR(PK, i) ((PK) + (size_t)((i) >> 7)*12*TILE + (size_t)((i) & 127)*128)

__global__ __launch_bounds__(1024, 1) void k_sink(const __half* __restrict__ P,
        float* __restrict__ fs, float* __restrict__ uvv,
        const float* __restrict__ xnrm, const float* __restrict__ ynrm,
        int* __restrict__ bars, int* __restrict__ flags,
        unsigned* __restrict__ cmin,
        int* __restrict__ done, double* __restrict__ partS,
        float* __restrict__ out){
    int tid = threadIdx.x;
    int lane = tid & 63;
    int wid = tid >> 6;
    int blk = (int)blockIdx.x;
    __shared__ int s_ch;
    __shared__ unsigned lmin[1536];
    __shared__ double red[1024];

    int b = blk / OTB, lb = blk - b*OTB;
    int gw = lb*16 + wid;
    const int NWV = OTB*16;     // 256 waves
    int* gbarp  = bars + b*64;
    int* gflagp = flags + b*64;
    const __half* P0 = P + (size_t)(b*4 + 0)*TSZ;
    float* fsb = fs + b*VSZ;
    float* uvb = uvv + b*VSZ;
    unsigned* cm = cmin + b*3*1536;

    int colb[3];
    #pragma unroll
    for (int it = 0; it < 3; ++it){
        int c = lane + it*64;
        colb[it] = ((c >> 4) << 7) + ((c & 15) << 3);
    }

    int lastT = 0;
    for (int t = 0; t < 30; ++t){
        unsigned* rdbuf = cm + ((t + 2) % 3)*1536;
        unsigned* wrbuf = cm + (t % 3)*1536;
        unsigned* rsbuf = cm + ((t + 1) % 3)*1536;
        if (tid == 0) s_ch = 0;
        for (int idx = tid; idx < 1536; idx += 1024) lmin[idx] = 0xFFFFFFFFu;
        float Au[3][8];
        #pragma unroll
        for (int it = 0; it < 3; ++it){
            uint4 k0 = *(const uint4*)(rdbuf + colb[it]);
            uint4 k1 = *(const uint4*)(rdbuf + colb[it] + 4);
            unsigned kk[8] = {k0.x, k0.y, k0.z, k0.w, k1.x, k1.y, k1.z, k1.w};
            #pragma unroll
            for (int e = 0; e < 8; ++e){
                int col = colb[it] + e;
                Au[it][e] = (col < NP) ? (-(funkey(kk[e]) + KADD)) : 3.0e38f;
            }
        }
        __syncthreads();
        float amin[3][8];
        #pragma unroll
        for (int it = 0; it < 3; ++it)
            #pragma unroll
            for (int e = 0; e < 8; ++e) amin[it][e] = 3.0e38f;
        int ch = 0;
        for (int i = gw; i < NP; i += NWV){
            const __half* rowb = ROWPTR(P0, i);
            uint4 pk[3];
            #pragma unroll
            for (int it = 0; it < 3; ++it){
                int c = lane + it*64, tt = c >> 4, q = c & 15;
                pk[it] = *(const uint4*)(rowb + (size_t)tt*TILE + q*8);
            }
            float cf[3][8];
            float m = 3.0e38f;
            #pragma unroll
            for (int it = 0; it < 3; ++it){
                float2 c0 = __half22float2(*(const __half2*)&pk[it].x);
                float2 c1 = __half22float2(*(const __half2*)&pk[it].y);
                float2 c2 = __half22float2(*(const __half2*)&pk[it].z);
                float2 c3 = __half22float2(*(const __half2*)&pk[it].w);
                cf[it][0] = c0.x; cf[it][1] = c0.y; cf[it][2] = c1.x; cf[it][3] = c1.y;
                cf[it][4] = c2.x; cf[it][5] = c2.y; cf[it][6] = c3.x; cf[it][7] = c3.y;
                #pragma unroll
                for (int e = 0; e < 8; ++e) m = fminf(m, Au[it][e] - cf[it][e]);
            }
            #pragma unroll
            for (int o = 1; o < 64; o <<= 1) m = fminf(m, __shfl_xor(m, o, 64));
            float nv = -(m + KADD);
            if (lane == 0){
                if (fabsf(nv - fsb[i]) > FTHR) ch = 1;
                fsb[i] = nv;
            }
            #pragma unroll
            for (int it = 0; it < 3; ++it)
                #pragma unroll
                for (int e = 0; e < 8; ++e)
                    amin[it][e] = fminf(amin[it][e], nv - cf[it][e]);
        }
        if (ch) s_ch = 1;
        #pragma unroll
        for (int it = 0; it < 3; ++it)
            #pragma unroll
            for (int e = 0; e < 8; ++e)
                atomicMin(&lmin[colb[it] + e], fkey(amin[it][e]));
        __syncthreads();
        for (int idx = tid; idx < 1536; idx += 1024)
            atomicMin(&wrbuf[idx], lmin[idx]);
        if (tid < 96) rsbuf[lb*96 + tid] = 0xFFFFFFFFu;
        if (tid == 0 && s_ch) atomicOr(&gflagp[t], 1);
        groupbar(&gbarp[t], OTB);
        lastT = t;
        int fA = __hip_atomic_load(&gflagp[t], __ATOMIC_RELAXED, __HIP_MEMORY_SCOPE_AGENT);
        if (fA == 0) break;
    }
    unsigned* fin = cm + (lastT % 3)*1536;
    for (int j = tid; j < NP; j += 1024)
        uvb[j] = -(funkey(fin[j]) + KADD);

    // ---- fused final: lb==0 computes batch partial; 4th arrival sums (fixed order) ----
    if (lb == 0){
        const float* xb = xnrm + b*VSZ;
        const float* yb = ynrm + b*VSZ;
        double s = 0.0;
        for (int i = tid; i < NP; i += 1024)
            s += (double)xb[i] + (double)yb[i] - (double)fsb[i] - (double)uvb[i];
        __syncthreads();
        red[tid] = s; __syncthreads();
        for (int w2 = 512; w2 > 0; w2 >>= 1){
            if (tid < w2) red[tid] += red[tid + w2];
            __syncthreads();
        }
        if (tid == 0){
            partS[b] = red[0];
            int old = __hip_atomic_fetch_add(done, 1, __ATOMIC_ACQ_REL, __HIP_MEMORY_SCOPE_AGENT);
            if (old == 3)
                out[0] = (float)((partS[0] + partS[1] + partS[2] + partS[3]) * (4.0/1500.0));
        }
    }
}

extern "C" void kernel_launch(void* const* d_in, const int* in_sizes, int n_in,
                              void* d_out, int out_size, void* d_ws, size_t ws_size,
                              hipStream_t stream) {
    const float* x = (const float*)d_in[0];
    const float* y = (const float*)d_in[1];
    float* out = (float*)d_out;

    __half* pxh = (__half*)d_ws;
    __half* pyh = pxh + (size_t)NB*NP*DP;
    float* csx = (float*)(pyh + (size_t)NB*NP*DP);
    float* csy = csx + NB*DD;
    float* fs  = csy + NB*DD;
    float* uv  = fs + NB*VSZ;
    float* xnrm = uv + NB*VSZ;
    float* ynrm = xnrm + NB*VSZ;
    int* bars  = (int*)(ynrm + NB*VSZ);                // 12*64 ints (bars.. then flags)
    int* flags = bars + 12*64;
    int* done  = flags + 12*64;                        // 2 ints (8B aligned)
    double* partS = (double*)(done + 2);               // 4 doubles
    unsigned* cmin = (unsigned*)(partS + 4);           // 4*3*1536 uints
    float* partial = (float*)(cmin + 4*3*1536);        // NCH*NB*2*DD floats
    float* smallEnd = partial + (size_t)NCH*NB*2*DD;
    size_t pOff = (((size_t)((char*)smallEnd - (char*)d_ws)) + 255) & ~(size_t)255;
    __half* P = (__half*)((char*)d_ws + pOff);

    k_colsum_p1<<<dim3(NCH + 1, NB, 2), 256, 0, stream>>>(x, y, partial, bars, cmin);
    k_colsum_p2<<<10, 256, 0, stream>>>(partial, csx, csy);

    k_normrow<<<3000, 256, 0, stream>>>(x, y, csx, csy, pxh, pyh, xnrm, uv, ynrm, cmin);

    k_gemm_mfma<<<576, 1024, 0, stream>>>(pxh, pyh, P);

    k_sink<<<4*OTB, 1024, 0, stream>>>(P, fs, uv, xnrm, ynrm, bars, flags, cmin, done, partS, out);
}